// Round 2
// baseline (462.154 us; speedup 1.0000x reference)
//
#include <hip/hip_runtime.h>
#include <stdint.h>

#define T      3072
#define CH     64
#define HEADS  32
#define WIDTH  1536
#define BM     64
#define BN     128
#define VSTR   132    // 128 + 4 pad (bf16 elems): 66 dwords = 2 mod 32 -> bank-volume floor
#define PSTR   132

typedef unsigned short u16;
typedef short short8 __attribute__((ext_vector_type(8)));   // 8 bf16 as i16
typedef float floatx4 __attribute__((ext_vector_type(4)));

__device__ __forceinline__ u16 f2b(float f) {   // fp32 -> bf16 bits, RNE
  union { float f; unsigned u; } x; x.f = f;
  unsigned u = x.u;
  return (u16)((u + 0x7fffu + ((u >> 16) & 1u)) >> 16);
}

// ---------------- pre-pass: fp32 qkv -> bf16 Qt/Kt (t,ch) and V (ch,t) ----------------
// grid (48 t-tiles, 32 heads, 3 roles), 256 threads
__global__ __launch_bounds__(256) void prepass(
    const float* __restrict__ qkv, u16* __restrict__ Qt,
    u16* __restrict__ Kt, u16* __restrict__ Vo) {
  __shared__ float tile[64][65];
  const int ttile = blockIdx.x, hh = blockIdx.y, role = blockIdx.z;
  const int b = hh >> 3, h = hh & 7;
  const int t0 = ttile * 64;
  const int tid = threadIdx.x;
  const float* src = qkv + (size_t)(b * WIDTH + role * 512 + h * CH) * T;

  if (role == 2) {                       // V: straight cast-copy, keep (ch, t)
    const int c = tid >> 2, seg = (tid & 3) * 16;
    const float4* s4 = (const float4*)(src + (size_t)c * T + t0 + seg);
    u16 o[16];
#pragma unroll
    for (int i = 0; i < 4; ++i) {
      float4 v = s4[i];
      o[4*i+0] = f2b(v.x); o[4*i+1] = f2b(v.y);
      o[4*i+2] = f2b(v.z); o[4*i+3] = f2b(v.w);
    }
    uint4* d = (uint4*)(Vo + (size_t)hh * CH * T + (size_t)c * T + t0 + seg);
    d[0] = *(uint4*)&o[0];
    d[1] = *(uint4*)&o[8];
  } else {                               // Q/K: LDS-tiled transpose to (t, ch)
    const int c = tid >> 2, seg = (tid & 3) * 16;
    const float4* s4 = (const float4*)(src + (size_t)c * T + t0 + seg);
#pragma unroll
    for (int i = 0; i < 4; ++i) {
      float4 v = s4[i];
      tile[c][seg + 4*i + 0] = v.x; tile[c][seg + 4*i + 1] = v.y;
      tile[c][seg + 4*i + 2] = v.z; tile[c][seg + 4*i + 3] = v.w;
    }
    __syncthreads();
    // Q gets full logit scale (1/8) * log2(e) folded in; K is unscaled
    const float scale = (role == 0) ? 0.18033688011112042f : 1.0f;
    const int t = tid >> 2, cs = (tid & 3) * 16;
    u16 o[16];
#pragma unroll
    for (int i = 0; i < 16; ++i) o[i] = f2b(tile[cs + i][t] * scale);
    u16* dst = (role == 0 ? Qt : Kt) + (size_t)hh * T * CH + (size_t)(t0 + t) * CH + cs;
    ((uint4*)dst)[0] = *(uint4*)&o[0];
    ((uint4*)dst)[1] = *(uint4*)&o[8];
  }
}

// ---------------- flash attention v2: static softmax, K from global, O=P*V^T ----------
// grid (48 q-tiles, 32 heads), 256 threads = 4 waves; 33792 B LDS -> 4 blocks/CU
__global__ __launch_bounds__(256, 4) void attn(
    const u16* __restrict__ Qt, const u16* __restrict__ Kt,
    const u16* __restrict__ Vg, float* __restrict__ out) {
  __shared__ __align__(16) u16 VL[CH * VSTR];         // [c][s] padded
  __shared__ __align__(16) u16 PL[4][16 * PSTR];      // per-wave [t][s] padded

  const int qtile = blockIdx.x, hh = blockIdx.y;
  const int tid = threadIdx.x;
  const int wave = tid >> 6, lane = tid & 63;
  const int l15 = lane & 15, quad = lane >> 4;
  const int t0 = qtile * BM;

  const u16* Qh = Qt + (size_t)hh * T * CH;
  const u16* Kh = Kt + (size_t)hh * T * CH;
  const u16* Vh = Vg + (size_t)hh * CH * T;

  // Q A-frags resident in regs: A[m=l15][k=quad*8+j]
  const short8 qf0 = *(const short8*)(Qh + (size_t)(t0 + wave * 16 + l15) * CH + quad * 8);
  const short8 qf1 = *(const short8*)(Qh + (size_t)(t0 + wave * 16 + l15) * CH + 32 + quad * 8);

  floatx4 oacc[4] = {{0,0,0,0},{0,0,0,0},{0,0,0,0},{0,0,0,0}};
  float lsum[4] = {0.f, 0.f, 0.f, 0.f};

  const int vs_c = tid >> 2, vs_o = (tid & 3) * 32;   // V staging: 64 B per thread

  u16* plw = PL[wave];

  for (int s0 = 0; s0 < T; s0 += BN) {
    __syncthreads();
    {
      const uint4* gv = (const uint4*)(Vh + (size_t)vs_c * T + s0 + vs_o);
      uint4 b0 = gv[0], b1 = gv[1], b2 = gv[2], b3 = gv[3];
      uint4* dv = (uint4*)(VL + vs_c * VSTR + vs_o);
      dv[0] = b0; dv[1] = b1; dv[2] = b2; dv[3] = b3;
    }
    __syncthreads();

    // S = Q^T K : K frags direct from global (L1/L2-cached)
    floatx4 sacc[8];
    const u16* Kp = Kh + (size_t)(s0 + l15) * CH + quad * 8;
#pragma unroll
    for (int nt = 0; nt < 8; ++nt) {
      const short8 kf0 = *(const short8*)(Kp + nt * 16 * CH);
      const short8 kf1 = *(const short8*)(Kp + nt * 16 * CH + 32);
      floatx4 z = {0.f, 0.f, 0.f, 0.f};
      z = __builtin_amdgcn_mfma_f32_16x16x32_bf16(qf0, kf0, z, 0, 0, 0);
      z = __builtin_amdgcn_mfma_f32_16x16x32_bf16(qf1, kf1, z, 0, 0, 0);
      sacc[nt] = z;
    }

    // static softmax: p = exp2(logit*log2e) (scale folded into Q); no running max.
    // Row t = quad*4+r, col s = nt*16+l15. Per-lane partial row sums, reduced at end.
#pragma unroll
    for (int r = 0; r < 4; ++r) {
#pragma unroll
      for (int nt = 0; nt < 8; ++nt) {
        float p = __builtin_amdgcn_exp2f(sacc[nt][r]);
        lsum[r] += p;
        plw[(quad * 4 + r) * PSTR + nt * 16 + l15] = f2b(p);
      }
    }

    // O[t][c] += P * V^T : A = P ([t][s] LDS), B = V^T (V is [c][s] LDS)
#pragma unroll
    for (int ks = 0; ks < 4; ++ks) {
      const short8 pf = *(const short8*)(plw + l15 * PSTR + ks * 32 + quad * 8);
#pragma unroll
      for (int mt = 0; mt < 4; ++mt) {
        const short8 vf = *(const short8*)(VL + (mt * 16 + l15) * VSTR + ks * 32 + quad * 8);
        oacc[mt] = __builtin_amdgcn_mfma_f32_16x16x32_bf16(pf, vf, oacc[mt], 0, 0, 0);
      }
    }
  }

  // epilogue: reduce row sums across the 16 s-lanes (same quad holds same rows)
  float linv[4];
#pragma unroll
  for (int r = 0; r < 4; ++r) {
    float s = lsum[r];
#pragma unroll
    for (int i = 0; i < 4; ++i) s += __shfl_xor(s, 1 << i, 64);
    linv[r] = 1.0f / s;
  }

  // O rows t = t0 + wave*16 + quad*4 + r ; cols c = mt*16 + l15. float4 over r.
  const int tbase = t0 + wave * 16 + quad * 4;
  const int band = tbase >> 10, tt = tbase & 1023;
  const int b = hh >> 3, h = hh & 7;
  float* obase = out + (size_t)band * (4 * 512 * 1024)
                     + (size_t)b * (512 * 1024)
                     + (size_t)(h * CH) * 1024 + tt;
#pragma unroll
  for (int mt = 0; mt < 4; ++mt) {
    const int c = mt * 16 + l15;
    float4 v;
    v.x = oacc[mt][0] * linv[0];
    v.y = oacc[mt][1] * linv[1];
    v.z = oacc[mt][2] * linv[2];
    v.w = oacc[mt][3] * linv[3];
    *(float4*)(obase + (size_t)c * 1024) = v;
  }
}

extern "C" void kernel_launch(void* const* d_in, const int* in_sizes, int n_in,
                              void* d_out, int out_size, void* d_ws, size_t ws_size,
                              hipStream_t stream) {
  (void)in_sizes; (void)n_in; (void)out_size; (void)ws_size;
  const float* qkv = (const float*)d_in[0];
  u16* Qt = (u16*)d_ws;                                   // 32*3072*64 bf16 each
  u16* Kt = Qt + (size_t)HEADS * T * CH;
  u16* Vo = Kt + (size_t)HEADS * T * CH;
  float* out = (float*)d_out;

  prepass<<<dim3(T / 64, HEADS, 3), 256, 0, stream>>>(qkv, Qt, Kt, Vo);
  attn<<<dim3(T / BM, HEADS), 256, 0, stream>>>(Qt, Kt, Vo, out);
}

// Round 3
// 315.528 us; speedup vs baseline: 1.4647x; 1.4647x over previous
//
#include <hip/hip_runtime.h>
#include <stdint.h>

#define T      3072
#define CH     64
#define HEADS  32
#define WIDTH  1536
#define BM     64
#define BN     64
#define NIT    (T / BN)
#define PSTR   68     // 64 + 4 pad: 34-dword stride == 2 mod 32 (R2-measured 0 conflicts)

typedef unsigned short u16;
typedef short short8 __attribute__((ext_vector_type(8)));   // 8 bf16 as i16
typedef float floatx4 __attribute__((ext_vector_type(4)));

__device__ __forceinline__ u16 f2b(float f) {   // fp32 -> bf16 bits, RNE
  union { float f; unsigned u; } x; x.f = f;
  unsigned u = x.u;
  return (u16)((u + 0x7fffu + ((u >> 16) & 1u)) >> 16);
}

__device__ __forceinline__ void gl_lds16(const void* g, void* l) {
  __builtin_amdgcn_global_load_lds(
      (const __attribute__((address_space(1))) uint32_t*)g,
      (__attribute__((address_space(3))) uint32_t*)l, 16, 0, 0);
}

// ---------------- pre-pass: fp32 qkv -> bf16 Qt/Kt (t,ch) and V (ch,t) ----------------
__global__ __launch_bounds__(256) void prepass(
    const float* __restrict__ qkv, u16* __restrict__ Qt,
    u16* __restrict__ Kt, u16* __restrict__ Vo) {
  __shared__ float tile[64][65];
  const int ttile = blockIdx.x, hh = blockIdx.y, role = blockIdx.z;
  const int b = hh >> 3, h = hh & 7;
  const int t0 = ttile * 64;
  const int tid = threadIdx.x;
  const float* src = qkv + (size_t)(b * WIDTH + role * 512 + h * CH) * T;

  if (role == 2) {                       // V: straight cast-copy, keep (ch, t)
    const int c = tid >> 2, seg = (tid & 3) * 16;
    const float4* s4 = (const float4*)(src + (size_t)c * T + t0 + seg);
    u16 o[16];
#pragma unroll
    for (int i = 0; i < 4; ++i) {
      float4 v = s4[i];
      o[4*i+0] = f2b(v.x); o[4*i+1] = f2b(v.y);
      o[4*i+2] = f2b(v.z); o[4*i+3] = f2b(v.w);
    }
    uint4* d = (uint4*)(Vo + (size_t)hh * CH * T + (size_t)c * T + t0 + seg);
    d[0] = *(uint4*)&o[0];
    d[1] = *(uint4*)&o[8];
  } else {                               // Q/K: LDS-tiled transpose to (t, ch)
    const int c = tid >> 2, seg = (tid & 3) * 16;
    const float4* s4 = (const float4*)(src + (size_t)c * T + t0 + seg);
#pragma unroll
    for (int i = 0; i < 4; ++i) {
      float4 v = s4[i];
      tile[c][seg + 4*i + 0] = v.x; tile[c][seg + 4*i + 1] = v.y;
      tile[c][seg + 4*i + 2] = v.z; tile[c][seg + 4*i + 3] = v.w;
    }
    __syncthreads();
    const float scale = (role == 0) ? 0.18033688011112042f : 1.0f;  // (1/8)*log2e on Q
    const int t = tid >> 2, cs = (tid & 3) * 16;
    u16 o[16];
#pragma unroll
    for (int i = 0; i < 16; ++i) o[i] = f2b(tile[cs + i][t] * scale);
    u16* dst = (role == 0 ? Qt : Kt) + (size_t)hh * T * CH + (size_t)(t0 + t) * CH + cs;
    ((uint4*)dst)[0] = *(uint4*)&o[0];
    ((uint4*)dst)[1] = *(uint4*)&o[8];
  }
}

// ---------------- flash attention v3: async dbuf staging, 1 barrier/iter --------------
// grid (48 q-tiles, 32 heads), 256 threads = 4 waves; 41472 B LDS -> 3 blocks/CU
__global__ __launch_bounds__(256, 3) void attn(
    const u16* __restrict__ Qt, const u16* __restrict__ Kt,
    const u16* __restrict__ Vg, float* __restrict__ out) {
  // Unpadded (global_load_lds requires lane-contiguous dest); XOR-swizzled 16B blocks:
  // phys_cb = cb ^ sw(row), sw(r) = (r + 2*(r>>3)) & 7
  __shared__ __align__(16) u16 KB[2][BN * CH];   // [s][c] 8192 B each
  __shared__ __align__(16) u16 VB[2][CH * BN];   // [c][s] 8192 B each
  __shared__ __align__(16) u16 PL[4][16 * PSTR]; // per-wave [t][s], padded (VALU-written)

  const int qtile = blockIdx.x, hh = blockIdx.y;
  const int tid = threadIdx.x;
  const int wave = tid >> 6, lane = tid & 63;
  const int l15 = lane & 15, quad = lane >> 4;
  const int t0 = qtile * BM;

  const u16* Qh = Qt + (size_t)hh * T * CH;
  const u16* Kh = Kt + (size_t)hh * T * CH;
  const u16* Vh = Vg + (size_t)hh * CH * T;

  // Q A-frags resident in regs: A[m=l15][k=quad*8+j]
  const short8 qf0 = *(const short8*)(Qh + (size_t)(t0 + wave * 16 + l15) * CH + quad * 8);
  const short8 qf1 = *(const short8*)(Qh + (size_t)(t0 + wave * 16 + l15) * CH + 32 + quad * 8);

  floatx4 oacc[4] = {{0,0,0,0},{0,0,0,0},{0,0,0,0},{0,0,0,0}};
  float lsum[4] = {0.f, 0.f, 0.f, 0.f};

  // staging geometry: 512 16B-blocks per tensor, wave w covers slots [w*128, w*128+128)
  int srow[2], scb[2];
#pragma unroll
  for (int j = 0; j < 2; ++j) {
    const int p = wave * 128 + j * 64 + lane;
    srow[j] = p >> 3;
    scb[j]  = (p & 7) ^ ((srow[j] + 2 * (srow[j] >> 3)) & 7);
  }

  // frag-read swizzle base: sw(nt*16+l15) = swl ^ (4*(nt&1))
  const int swl = (l15 + 2 * (l15 >> 3)) & 7;
  u16* plw = PL[wave];

#define STAGE(buf, s0)                                                              \
  do {                                                                              \
    _Pragma("unroll")                                                               \
    for (int j = 0; j < 2; ++j)                                                     \
      gl_lds16(Kh + (size_t)((s0) + srow[j]) * CH + scb[j] * 8,                     \
               &KB[buf][(wave * 128 + j * 64) * 8]);                                \
    _Pragma("unroll")                                                               \
    for (int j = 0; j < 2; ++j)                                                     \
      gl_lds16(Vh + (size_t)srow[j] * T + (s0) + scb[j] * 8,                        \
               &VB[buf][(wave * 128 + j * 64) * 8]);                                \
  } while (0)

  STAGE(0, 0);

  for (int it = 0; it < NIT; ++it) {
    const int cur = it & 1;
    __syncthreads();                      // buf[cur] staged (vmcnt drained here)
    if (it + 1 < NIT) STAGE(cur ^ 1, (it + 1) * BN);   // async, overlaps compute

    const u16* KL = KB[cur];
    const u16* VL = VB[cur];

    // S = Q^T K : 4 n-tiles x (K=64 -> 2 chained MFMAs)
    floatx4 sacc[4];
#pragma unroll
    for (int nt = 0; nt < 4; ++nt) {
      const int ph0 = quad ^ swl ^ ((nt & 1) * 4);
      const int base = (nt * 16 + l15) * CH;
      const short8 kf0 = *(const short8*)(KL + base + ph0 * 8);
      const short8 kf1 = *(const short8*)(KL + base + (ph0 ^ 4) * 8);
      floatx4 z = {0.f, 0.f, 0.f, 0.f};
      z = __builtin_amdgcn_mfma_f32_16x16x32_bf16(qf0, kf0, z, 0, 0, 0);
      z = __builtin_amdgcn_mfma_f32_16x16x32_bf16(qf1, kf1, z, 0, 0, 0);
      sacc[nt] = z;
    }

    // static softmax (scale+log2e folded into Q): row t=quad*4+r, col s=nt*16+l15
#pragma unroll
    for (int r = 0; r < 4; ++r) {
#pragma unroll
      for (int nt = 0; nt < 4; ++nt) {
        float p = __builtin_amdgcn_exp2f(sacc[nt][r]);
        lsum[r] += p;
        plw[(quad * 4 + r) * PSTR + nt * 16 + l15] = f2b(p);
      }
    }

    // O[t][c] += P * V^T : A = P ([t][s] LDS), B = V^T (V is [c][s] LDS, swizzled)
#pragma unroll
    for (int ks = 0; ks < 2; ++ks) {
      const short8 pf = *(const short8*)(plw + l15 * PSTR + ks * 32 + quad * 8);
#pragma unroll
      for (int mt = 0; mt < 4; ++mt) {
        const int ph = quad ^ swl ^ ((mt & 1) * 4) ^ (ks * 4);
        const short8 vf = *(const short8*)(VL + (mt * 16 + l15) * BN + ph * 8);
        oacc[mt] = __builtin_amdgcn_mfma_f32_16x16x32_bf16(pf, vf, oacc[mt], 0, 0, 0);
      }
    }
  }

  // epilogue: reduce row sums across the 16 s-lanes (quad q holds rows 4q..4q+3)
  float linv[4];
#pragma unroll
  for (int r = 0; r < 4; ++r) {
    float s = lsum[r];
#pragma unroll
    for (int i = 0; i < 4; ++i) s += __shfl_xor(s, 1 << i, 64);
    linv[r] = 1.0f / s;
  }

  // O rows t = t0 + wave*16 + quad*4 + r ; cols c = mt*16 + l15. float4 over r.
  const int tbase = t0 + wave * 16 + quad * 4;
  const int band = tbase >> 10, tt = tbase & 1023;
  const int b = hh >> 3, h = hh & 7;
  float* obase = out + (size_t)band * (4 * 512 * 1024)
                     + (size_t)b * (512 * 1024)
                     + (size_t)(h * CH) * 1024 + tt;
#pragma unroll
  for (int mt = 0; mt < 4; ++mt) {
    const int c = mt * 16 + l15;
    float4 v;
    v.x = oacc[mt][0] * linv[0];
    v.y = oacc[mt][1] * linv[1];
    v.z = oacc[mt][2] * linv[2];
    v.w = oacc[mt][3] * linv[3];
    *(float4*)(obase + (size_t)c * 1024) = v;
  }
}

extern "C" void kernel_launch(void* const* d_in, const int* in_sizes, int n_in,
                              void* d_out, int out_size, void* d_ws, size_t ws_size,
                              hipStream_t stream) {
  (void)in_sizes; (void)n_in; (void)out_size; (void)ws_size;
  const float* qkv = (const float*)d_in[0];
  u16* Qt = (u16*)d_ws;                                   // 32*3072*64 bf16 each
  u16* Kt = Qt + (size_t)HEADS * T * CH;
  u16* Vo = Kt + (size_t)HEADS * T * CH;
  float* out = (float*)d_out;

  prepass<<<dim3(T / 64, HEADS, 3), 256, 0, stream>>>(qkv, Qt, Kt, Vo);
  attn<<<dim3(T / BM, HEADS), 256, 0, stream>>>(Qt, Kt, Vo, out);
}

// Round 4
// 216.589 us; speedup vs baseline: 2.1338x; 1.4568x over previous
//
#include <hip/hip_runtime.h>
#include <hip/hip_bf16.h>
#include <stdint.h>

#define T      3072
#define CH     64
#define HEADS  32
#define BM     128
#define BN     64
#define NIT    (T / BN)
#define PSTR   72     // row stride (u16): 144 B = 16B-aligned for b128 P reads

typedef unsigned short u16;
typedef short short8 __attribute__((ext_vector_type(8)));   // 8 bf16 as i16
typedef float floatx4 __attribute__((ext_vector_type(4)));

__device__ __forceinline__ unsigned pk2(float a, float b) {  // 2 fp32 -> packed bf16x2 (RNE)
  union { __hip_bfloat162 h; unsigned u; } cv;
  cv.h = __float22bfloat162_rn(float2{a, b});
  return cv.u;
}

__device__ __forceinline__ void gl_lds16(const void* g, void* l) {
  __builtin_amdgcn_global_load_lds(
      (const __attribute__((address_space(1))) uint32_t*)g,
      (__attribute__((address_space(3))) uint32_t*)l, 16, 0, 0);
}

// ---------- prepass A: Q/K transpose (ch,t)->(t,ch) with bf16 cast ----------
// grid (48 t-tiles, 32 heads, 2 roles), 256 threads
__global__ __launch_bounds__(256) void qktrans(
    const float* __restrict__ qkv, u16* __restrict__ Qt, u16* __restrict__ Kt) {
  __shared__ __align__(16) u16 tl[64][PSTR];          // [t][c]
  const int ttile = blockIdx.x, hh = blockIdx.y, role = blockIdx.z;
  const int b = hh >> 3, h = hh & 7;
  const int t0 = ttile * 64;
  const int tid = threadIdx.x;
  const float* src = qkv + (size_t)(b * 1536 + role * 512 + h * CH) * T;
  const float scale = (role == 0) ? 0.18033688011112042f : 1.0f;  // (1/8)*log2e on Q

#pragma unroll
  for (int p = 0; p < 2; ++p) {                        // 32 c-rows per pass
    const int c0 = p * 32 + ((tid >> 4) << 1);         // even
    const int ts = (tid & 15) * 4;                     // 256B contiguous per c-row
    float4 a = *(const float4*)(src + (size_t)c0 * T + t0 + ts);
    float4 c = *(const float4*)(src + (size_t)(c0 + 1) * T + t0 + ts);
    *(unsigned*)&tl[ts + 0][c0] = pk2(a.x * scale, c.x * scale);
    *(unsigned*)&tl[ts + 1][c0] = pk2(a.y * scale, c.y * scale);
    *(unsigned*)&tl[ts + 2][c0] = pk2(a.z * scale, c.z * scale);
    *(unsigned*)&tl[ts + 3][c0] = pk2(a.w * scale, c.w * scale);
  }
  __syncthreads();
  u16* dst = (role == 0 ? Qt : Kt) + (size_t)hh * T * CH;
#pragma unroll
  for (int q = 0; q < 2; ++q) {                        // 1KB/wave contiguous stores
    const int t = q * 32 + (tid >> 3);
    const int cc = (tid & 7) * 8;
    uint4 v = *(const uint4*)&tl[t][cc];
    *(uint4*)(dst + (size_t)(t0 + t) * CH + cc) = v;
  }
}

// ---------- prepass B: V flat cast (layouts identical) ----------
// grid (768, 4 batches), 256 threads, 8 elems/thread
__global__ __launch_bounds__(256) void vcast(
    const float* __restrict__ qkv, u16* __restrict__ Vo) {
  const int b = blockIdx.y;
  const size_t i = ((size_t)blockIdx.x * 256 + threadIdx.x) * 8;
  const float4* s4 = (const float4*)(qkv + (size_t)b * 1536 * T + (size_t)1024 * T + i);
  float4 a = s4[0], c = s4[1];
  uint4 o;
  o.x = pk2(a.x, a.y); o.y = pk2(a.z, a.w);
  o.z = pk2(c.x, c.y); o.w = pk2(c.z, c.w);
  *(uint4*)(Vo + (size_t)b * 512 * T + i) = o;
}

// ---------- flash attention v4: S^T form, BM=128, packed P, async dbuf ----------
// grid (24 q-tiles, 32 heads), 256 threads = 4 waves; 51200 B LDS -> 3 blocks/CU
__global__ __launch_bounds__(256, 3) void attn(
    const u16* __restrict__ Qt, const u16* __restrict__ Kt,
    const u16* __restrict__ Vg, float* __restrict__ out) {
  __shared__ __align__(16) u16 KB[2][BN * CH];    // [s][c] 8 KB each, xor-swizzled
  __shared__ __align__(16) u16 VB[2][CH * BN];    // [c][s] 8 KB each, xor-swizzled
  __shared__ __align__(16) u16 PL[4][32 * PSTR];  // per-wave [t][s]

  const int qtile = blockIdx.x, hh = blockIdx.y;
  const int tid = threadIdx.x;
  const int wave = tid >> 6, lane = tid & 63;
  const int l15 = lane & 15, quad = lane >> 4;
  const int t0 = qtile * BM + wave * 32;

  const u16* Qh = Qt + (size_t)hh * T * CH;
  const u16* Kh = Kt + (size_t)hh * T * CH;
  const u16* Vh = Vg + (size_t)hh * CH * T;

  // Q B-frags resident: B[n=t=l15(+16tq)][k=kc*32+quad*8+j]
  short8 qf[2][2];
#pragma unroll
  for (int tq = 0; tq < 2; ++tq)
#pragma unroll
    for (int kc = 0; kc < 2; ++kc)
      qf[tq][kc] = *(const short8*)(Qh + (size_t)(t0 + tq * 16 + l15) * CH + kc * 32 + quad * 8);

  floatx4 oacc[2][4] = {};
  float lsum[2][2] = {};

  // staging: 512 16B-slots per tensor; swizzle phys_cb = cb ^ ((row + 2*(row>>3))&7)
  int srow[2], scb[2];
#pragma unroll
  for (int j = 0; j < 2; ++j) {
    const int p = wave * 128 + j * 64 + lane;
    srow[j] = p >> 3;
    scb[j]  = (p & 7) ^ ((srow[j] + 2 * (srow[j] >> 3)) & 7);
  }
  const int swl = (l15 + 2 * (l15 >> 3)) & 7;
  u16* plw = PL[wave];

#define STAGE(buf, s0)                                                              \
  do {                                                                              \
    _Pragma("unroll")                                                               \
    for (int j = 0; j < 2; ++j)                                                     \
      gl_lds16(Kh + (size_t)((s0) + srow[j]) * CH + scb[j] * 8,                     \
               &KB[buf][(wave * 128 + j * 64) * 8]);                                \
    _Pragma("unroll")                                                               \
    for (int j = 0; j < 2; ++j)                                                     \
      gl_lds16(Vh + (size_t)srow[j] * T + (s0) + scb[j] * 8,                        \
               &VB[buf][(wave * 128 + j * 64) * 8]);                                \
  } while (0)

  STAGE(0, 0);

  for (int it = 0; it < NIT; ++it) {
    const int cur = it & 1;
    __syncthreads();                                   // buf[cur] ready
    if (it + 1 < NIT) STAGE(cur ^ 1, (it + 1) * BN);   // async prefetch

    const u16* KL = KB[cur];
    const u16* VL = VB[cur];

    // S^T = K Q^T : A=K frag (LDS), B=Q frag (regs).
    // sacc[tq][nt][r] = S[t = l15+16tq][s = nt*16 + quad*4 + r]
    floatx4 sacc[2][4];
#pragma unroll
    for (int nt = 0; nt < 4; ++nt) {
      const int ph0 = quad ^ swl ^ ((nt & 1) * 4);
      const int base = (nt * 16 + l15) * CH;
      const short8 kf0 = *(const short8*)(KL + base + ph0 * 8);
      const short8 kf1 = *(const short8*)(KL + base + (ph0 ^ 4) * 8);
#pragma unroll
      for (int tq = 0; tq < 2; ++tq) {
        floatx4 z = {0.f, 0.f, 0.f, 0.f};
        z = __builtin_amdgcn_mfma_f32_16x16x32_bf16(kf0, qf[tq][0], z, 0, 0, 0);
        z = __builtin_amdgcn_mfma_f32_16x16x32_bf16(kf1, qf[tq][1], z, 0, 0, 0);
        sacc[tq][nt] = z;
      }
    }

    // static softmax: lane's 4 values are consecutive s at fixed t -> packed b64 write
#pragma unroll
    for (int tq = 0; tq < 2; ++tq)
#pragma unroll
      for (int nt = 0; nt < 4; ++nt) {
        floatx4 sv = sacc[tq][nt];
        float p0 = __builtin_amdgcn_exp2f(sv[0]);
        float p1 = __builtin_amdgcn_exp2f(sv[1]);
        float p2 = __builtin_amdgcn_exp2f(sv[2]);
        float p3 = __builtin_amdgcn_exp2f(sv[3]);
        lsum[tq][nt & 1] += (p0 + p1) + (p2 + p3);
        uint2 w; w.x = pk2(p0, p1); w.y = pk2(p2, p3);
        *(uint2*)(plw + (l15 + tq * 16) * PSTR + nt * 16 + quad * 4) = w;
      }

    // O = P V^T : A=P [t][s], B=V^T (V is [c][s])
#pragma unroll
    for (int ks = 0; ks < 2; ++ks) {
      short8 pf0 = *(const short8*)(plw + l15 * PSTR + ks * 32 + quad * 8);
      short8 pf1 = *(const short8*)(plw + (l15 + 16) * PSTR + ks * 32 + quad * 8);
#pragma unroll
      for (int mt = 0; mt < 4; ++mt) {
        const int ph = quad ^ swl ^ ((mt & 1) * 4) ^ (ks * 4);
        const short8 vf = *(const short8*)(VL + (mt * 16 + l15) * BN + ph * 8);
        oacc[0][mt] = __builtin_amdgcn_mfma_f32_16x16x32_bf16(pf0, vf, oacc[0][mt], 0, 0, 0);
        oacc[1][mt] = __builtin_amdgcn_mfma_f32_16x16x32_bf16(pf1, vf, oacc[1][mt], 0, 0, 0);
      }
    }
  }

  // epilogue: full row sums (reduce across quads), then per-output-row linv via shfl
  float ls[2];
#pragma unroll
  for (int tq = 0; tq < 2; ++tq) {
    float s = lsum[tq][0] + lsum[tq][1];
    s += __shfl_xor(s, 16, 64);
    s += __shfl_xor(s, 32, 64);
    ls[tq] = s;                                        // sum for row l15 + 16tq
  }
  float linv[2][4];
#pragma unroll
  for (int tq = 0; tq < 2; ++tq)
#pragma unroll
    for (int r = 0; r < 4; ++r)
      linv[tq][r] = 1.0f / __shfl(ls[tq], quad * 4 + r, 64);

  // O rows t = t0 + tq*16 + quad*4 + r ; cols c = mt*16 + l15 ; float4 over r
  const int b = hh >> 3, h = hh & 7;
#pragma unroll
  for (int tq = 0; tq < 2; ++tq) {
    const int tg = t0 + tq * 16 + quad * 4;
    const int band = tg >> 10, tt = tg & 1023;
    float* obase = out + (size_t)band * (4 * 512 * 1024)
                       + (size_t)b * (512 * 1024)
                       + (size_t)(h * CH) * 1024 + tt;
#pragma unroll
    for (int mt = 0; mt < 4; ++mt) {
      const int c = mt * 16 + l15;
      float4 v;
      v.x = oacc[tq][mt][0] * linv[tq][0];
      v.y = oacc[tq][mt][1] * linv[tq][1];
      v.z = oacc[tq][mt][2] * linv[tq][2];
      v.w = oacc[tq][mt][3] * linv[tq][3];
      *(float4*)(obase + (size_t)c * 1024) = v;
    }
  }
}

extern "C" void kernel_launch(void* const* d_in, const int* in_sizes, int n_in,
                              void* d_out, int out_size, void* d_ws, size_t ws_size,
                              hipStream_t stream) {
  (void)in_sizes; (void)n_in; (void)out_size; (void)ws_size;
  const float* qkv = (const float*)d_in[0];
  u16* Qt = (u16*)d_ws;                                 // 3 x 12.6 MB bf16
  u16* Kt = Qt + (size_t)HEADS * T * CH;
  u16* Vo = Kt + (size_t)HEADS * T * CH;
  float* out = (float*)d_out;

  qktrans<<<dim3(T / 64, HEADS, 2), 256, 0, stream>>>(qkv, Qt, Kt);
  vcast<<<dim3(768, 4), 256, 0, stream>>>(qkv, Vo);
  attn<<<dim3(T / BM, HEADS), 256, 0, stream>>>(Qt, Kt, Vo, out);
}